// Round 1
// 499.093 us; speedup vs baseline: 1.0081x; 1.0081x over previous
//
#include <hip/hip_runtime.h>
#include <stdint.h>

// MAHA decoder block, MI355X/gfx950. Round 6: BK=64 + MT=8 GEMM (4x MFMA per
// barrier interval), V-transpose fused into QKV epilogue, BTgu pad zero-fill.
// B=2, N=2048, D=1024, H=16(dh=64), L=3, R=2, HID=2734(->2816), fp32 I/O.

#define B_   2
#define N_   2048
#define D_   1024
#define H_   16
#define DH_  64
#define HID_ 2734
#define HIDP 2816
#define CNT  (B_*N_*D_)   // 4194304
#define LOG2E 1.4426950408889634f

typedef unsigned short u16;
typedef __attribute__((ext_vector_type(8))) short short8;
typedef __attribute__((ext_vector_type(4))) float f32x4;
typedef __attribute__((ext_vector_type(4))) uint16_t u16x4;

__device__ __forceinline__ u16 f2bf(float f) {
  uint32_t u = __builtin_bit_cast(uint32_t, f);
  u += 0x7fffu + ((u >> 16) & 1u);          // RNE
  return (u16)(u >> 16);
}
__device__ __forceinline__ float bf2f(u16 h) {
  uint32_t u = ((uint32_t)h) << 16;
  return __builtin_bit_cast(float, u);
}
__device__ __forceinline__ uint32_t pkbf(float a, float b) {
  return (uint32_t)f2bf(a) | ((uint32_t)f2bf(b) << 16);
}
__device__ __forceinline__ void gload_lds16(const void* g, void* l) {
  __builtin_amdgcn_global_load_lds(
      (const __attribute__((address_space(1))) uint32_t*)g,
      (__attribute__((address_space(3))) uint32_t*)l, 16, 0, 0);
}

// ============ batched weight prep: all fp32->bf16 transposes + Wdec convert + SC zero ====
// blocks: [0,9216) QKV weight transposes | [9216,10240) Wo | [10240,13056) Wg(gate-ilv)
// [13056,15872) Wu(up-ilv) | [15872,18688) Wdn | [18688,21760) Wdec plain convert
// [21760,21924) BTgu pad-row zero-fill (rows 5454,5455,5470..5631)
__global__ __launch_bounds__(256) void wprep_k(const float* __restrict__ Wdec, const float* __restrict__ Wq,
                                               const float* __restrict__ Wk, const float* __restrict__ Wv,
                                               const float* __restrict__ Wo, const float* __restrict__ Wg,
                                               const float* __restrict__ Wu, const float* __restrict__ Wdn,
                                               u16* __restrict__ A_wp, u16* __restrict__ WdecB,
                                               u16* __restrict__ WoT, u16* __restrict__ BTgu,
                                               u16* __restrict__ WdnT, float* __restrict__ SCb) {
  const int bid = blockIdx.x;
  if (bid >= 21760) {
    int bid0 = bid - 21760;
    int row = (bid0 < 2) ? (5454 + bid0) : (5470 + (bid0 - 2));
    u16x4 zz; zz[0]=0; zz[1]=0; zz[2]=0; zz[3]=0;
    *(u16x4*)(BTgu + (size_t)row*1024 + threadIdx.x*4) = zz;
    return;
  }
  if (bid >= 18688) {
    if (bid == 18688 && threadIdx.x < 64) SCb[threadIdx.x] = 0.f;
    int i = (bid - 18688)*1024 + threadIdx.x*4;
    float4 v = *(const float4*)(Wdec + i);
    u16x4 o; o[0]=f2bf(v.x); o[1]=f2bf(v.y); o[2]=f2bf(v.z); o[3]=f2bf(v.w);
    *(u16x4*)(WdecB + i) = o;
    return;
  }
  const float* src; u16* dst; int K, N, KP; float scale; int imode; int bx, by;
  if (bid < 9216) {
    int j = bid >> 10, t = bid & 1023; bx = t & 31; by = t >> 5;
    int l = j / 3, which = j - l*3;
    src = which==0 ? Wq + (size_t)l*1048576 : which==1 ? Wk + (size_t)l*1048576 : Wv;
    dst = A_wp + (size_t)(l*3072 + which*1024)*1024;
    K = 1024; N = 1024; KP = 1024; scale = (which==0) ? 0.125f*LOG2E : 1.f; imode = 0;
  } else if (bid < 10240) {
    int t = bid - 9216; bx = t & 31; by = t >> 5;
    src = Wo; dst = WoT; K=1024; N=1024; KP=1024; scale=1.f; imode=0;
  } else if (bid < 13056) {
    int t = bid - 10240; bx = t % 88; by = t / 88;
    src = Wg; dst = BTgu; K=1024; N=HID_; KP=1024; scale=1.f; imode=1;
  } else if (bid < 15872) {
    int t = bid - 13056; bx = t % 88; by = t / 88;
    src = Wu; dst = BTgu; K=1024; N=HID_; KP=1024; scale=1.f; imode=2;
  } else {
    int t = bid - 15872; bx = t & 31; by = t >> 5;
    src = Wdn; dst = WdnT; K=HID_; N=1024; KP=HIDP; scale=1.f; imode=0;
  }
  __shared__ float tt[32][33];
  const int tx = threadIdx.x & 31, ty = threadIdx.x >> 5;
  const int nb = bx*32, kb = by*32;
  #pragma unroll
  for (int i = 0; i < 4; i++) {
    int k = kb + ty + i*8, n = nb + tx;
    tt[ty + i*8][tx] = (k < K && n < N) ? src[(size_t)k * N + n] * scale : 0.f;
  }
  __syncthreads();
  #pragma unroll
  for (int i = 0; i < 4; i++) {
    int n = nb + ty + i*8, k = kb + tx;
    int r;
    if (imode == 0) r = n;
    else if (imode == 1) r = ((n>>4)<<5) + (n&15);
    else r = ((n>>4)<<5) + 16 + (n&15);
    dst[(size_t)r * KP + k] = f2bf(tt[tx][ty + i*8]);
  }
}

// ---------------- attention RMSNorm: 2 rows per block + fp32 pooled row ----------------
__global__ __launch_bounds__(256) void rmsA_k(const float* __restrict__ x, const float* __restrict__ w,
                                              u16* __restrict__ xn, u16* __restrict__ xp1) {
  const int j = blockIdx.x;
  const float* xr0 = x + (size_t)(2*j) * D_;
  const float* xr1 = xr0 + D_;
  float a0[4], a1[4], wv[4];
  float ss0 = 0.f, ss1 = 0.f;
  #pragma unroll
  for (int i = 0; i < 4; i++) {
    int c = threadIdx.x + i*256;
    a0[i] = xr0[c]; a1[i] = xr1[c]; wv[i] = w[c];
    ss0 += a0[i]*a0[i]; ss1 += a1[i]*a1[i];
  }
  #pragma unroll
  for (int o = 1; o < 64; o <<= 1) { ss0 += __shfl_xor(ss0, o); ss1 += __shfl_xor(ss1, o); }
  __shared__ float r0[4], r1[4];
  if ((threadIdx.x & 63) == 0) { r0[threadIdx.x >> 6] = ss0; r1[threadIdx.x >> 6] = ss1; }
  __syncthreads();
  float sc0 = rsqrtf((r0[0]+r0[1]+r0[2]+r0[3]) * (1.f/D_) + 1e-6f);
  float sc1 = rsqrtf((r1[0]+r1[1]+r1[2]+r1[3]) * (1.f/D_) + 1e-6f);
  #pragma unroll
  for (int i = 0; i < 4; i++) {
    int c = threadIdx.x + i*256;
    float xa = a0[i]*wv[i]*sc0, xb = a1[i]*wv[i]*sc1;
    xn[(size_t)(2*j)*D_ + c]     = f2bf(xa);
    xn[(size_t)(2*j)*D_ + D_ + c] = f2bf(xb);
    xp1[(size_t)j*D_ + c] = f2bf(0.5f*(xa + xb));
  }
}

// ---------------- avg-pool by 2 along seq (bf16), 4-wide; No = 1<<lg ----------------
__global__ __launch_bounds__(256) void pool_k(const u16* __restrict__ in, u16* __restrict__ out, int lg) {
  const int No = 1 << lg;
  const int total4 = B_ * No * 256;
  for (int i = blockIdx.x*256 + threadIdx.x; i < total4; i += gridDim.x*256) {
    int d4 = i & 255; int j = (i >> 8) & (No - 1); int b = i >> (8 + lg);
    size_t src = ((size_t)(b*2*No + 2*j) << 10) + d4*4;
    u16x4 a = *(const u16x4*)(in + src);
    u16x4 c = *(const u16x4*)(in + src + 1024);
    u16x4 o;
    #pragma unroll
    for (int t = 0; t < 4; t++) o[t] = f2bf(0.5f * (bf2f(a[t]) + bf2f(c[t])));
    *(u16x4*)(out + (size_t)i*4) = o;
  }
}

// ---------------- MFMA GEMM, C = A[M,K] * BT[N,K]^T; block = MT*32 x 128, BK=64 ----
// MODE 1: bf16 store. MODE 2: fp32 out = SCp[11]*X1 + SCp[12]*acc. MODE 3: silu(gate)*up
// epilogue (BT interleaved at 16-col granularity), bf16 h store with row stride HIDP.
// MODE 4: QKV epilogue: cols<2048 bf16 store (stride N); cols>=2048 V stored transposed
// into Cv2 (per-level [b][c][n] layout), V not written to C.
template<int MT, int MODE>
__global__ __launch_bounds__(256, 2) void gemm_t(const u16* __restrict__ A, const u16* __restrict__ BT,
                                                 void* __restrict__ Cv, void* __restrict__ Cv2,
                                                 const float* __restrict__ X1,
                                                 const float* __restrict__ SCp,
                                                 int N, int K, int t1, int t2, unsigned int bt_stride) {
  __shared__ __align__(16) u16 As[MT*32*64];
  __shared__ __align__(16) u16 Bs[128*64];
  const int tid = threadIdx.x;
  const int lane = tid & 63, wid = tid >> 6;
  const int quad = lane >> 4, c16 = lane & 15;
  const int y = blockIdx.y;
  const int m0 = y * (MT*32), n0 = blockIdx.x * 128;
  const int wm = wid >> 1, wn = wid & 1;
  const int level = (y >= t2) ? 2 : ((y >= t1) ? 1 : 0);
  BT += (size_t)level * bt_stride;

  f32x4 acc[MT][4];
  #pragma unroll
  for (int i = 0; i < MT; i++)
    #pragma unroll
    for (int j = 0; j < 4; j++) acc[i][j] = f32x4{0.f,0.f,0.f,0.f};

  // staging: 1KB wave-chunks of 8 rows x 64 cols; source pre-swizzled so that the
  // swizzled read (chunk ^ (row&7)) is bank-spread (2 lanes/bank).
  const int srow = lane >> 3;         // row within chunk
  const int schunk = lane & 7;        // 8-elem (16B) chunk within 64-col row
  for (int k0 = 0; k0 < K; k0 += 64) {
    #pragma unroll
    for (int t = 0; t < MT; t++) {
      int idx = wid*MT + t;
      int row = idx*8 + srow;
      int g = (schunk ^ (row & 7)) * 8;
      gload_lds16(A + (size_t)(m0+row)*K + k0 + g, As + idx*512);
    }
    #pragma unroll
    for (int t = 0; t < 4; t++) {
      int idx = wid*4 + t;
      int row = idx*8 + srow;
      int g = (schunk ^ (row & 7)) * 8;
      gload_lds16(BT + (size_t)(n0+row)*K + k0 + g, Bs + idx*512);
    }
    __syncthreads();
    #pragma unroll
    for (int kh = 0; kh < 2; kh++) {
      short8 af[MT], bfr[4];
      #pragma unroll
      for (int mt = 0; mt < MT; mt++) {
        int ar = wm*(MT*16) + mt*16 + c16;
        int ck = (kh*4 + quad) ^ (ar & 7);
        af[mt] = *(const short8*)(As + ar*64 + ck*8);
      }
      #pragma unroll
      for (int nt = 0; nt < 4; nt++) {
        int br = wn*64 + nt*16 + c16;
        int ck = (kh*4 + quad) ^ (br & 7);
        bfr[nt] = *(const short8*)(Bs + br*64 + ck*8);
      }
      #pragma unroll
      for (int mt = 0; mt < MT; mt++)
        #pragma unroll
        for (int nt = 0; nt < 4; nt++)
          acc[mt][nt] = __builtin_amdgcn_mfma_f32_16x16x32_bf16(af[mt], bfr[nt], acc[mt][nt], 0, 0, 0);
    }
    __syncthreads();
  }
  if (MODE == 1) {
    u16* C = (u16*)Cv;
    #pragma unroll
    for (int mt = 0; mt < MT; mt++)
      #pragma unroll
      for (int nt = 0; nt < 4; nt++)
        #pragma unroll
        for (int r = 0; r < 4; r++) {
          int row = m0 + wm*(MT*16) + mt*16 + quad*4 + r;
          int col = n0 + wn*64 + nt*16 + c16;
          C[(size_t)row * N + col] = f2bf(acc[mt][nt][r]);
        }
  } else if (MODE == 2) {
    float* C = (float*)Cv;
    const float q0 = SCp[11], q1 = SCp[12];
    #pragma unroll
    for (int mt = 0; mt < MT; mt++)
      #pragma unroll
      for (int nt = 0; nt < 4; nt++)
        #pragma unroll
        for (int r = 0; r < 4; r++) {
          int row = m0 + wm*(MT*16) + mt*16 + quad*4 + r;
          int col = n0 + wn*64 + nt*16 + c16;
          size_t o = (size_t)row * N + col;
          C[o] = q0 * X1[o] + q1 * acc[mt][nt][r];
        }
  } else if (MODE == 3) {
    u16* Hc = (u16*)Cv;
    const int hbase = (n0 >> 1) + wn*32;
    #pragma unroll
    for (int mt = 0; mt < MT; mt++)
      #pragma unroll
      for (int r = 0; r < 4; r++) {
        int row = m0 + wm*(MT*16) + mt*16 + quad*4 + r;
        #pragma unroll
        for (int pr = 0; pr < 2; pr++) {
          float g = acc[mt][2*pr][r], u = acc[mt][2*pr+1][r];
          float h = g / (1.f + __expf(-g)) * u;
          Hc[(size_t)row * HIDP + hbase + pr*16 + c16] = f2bf(h);
        }
      }
  } else {  // MODE 4
    if (n0 < 2048) {
      u16* C = (u16*)Cv;
      #pragma unroll
      for (int mt = 0; mt < MT; mt++)
        #pragma unroll
        for (int nt = 0; nt < 4; nt++)
          #pragma unroll
          for (int r = 0; r < 4; r++) {
            int row = m0 + wm*(MT*16) + mt*16 + quad*4 + r;
            int col = n0 + wn*64 + nt*16 + c16;
            C[(size_t)row * N + col] = f2bf(acc[mt][nt][r]);
          }
    } else {
      const int Nl = 2048 >> level;
      const int lvbase = (level==0) ? 0 : (level==1) ? 4096 : 6144;
      const size_t vtoff = (level==0) ? 0 : (level==1) ? 4194304 : 6291456;
      u16* VT = (u16*)Cv2 + vtoff;
      #pragma unroll
      for (int mt = 0; mt < MT; mt++) {
        int rowg = m0 + wm*(MT*16) + mt*16 + quad*4;   // r=0 row; +3 stays in-row-group
        int nloc = rowg - lvbase;
        int b = nloc / Nl;              // Nl is power of two
        int n = nloc - b*Nl;
        #pragma unroll
        for (int nt = 0; nt < 4; nt++) {
          int c = n0 - 2048 + wn*64 + nt*16 + c16;
          u16x4 o;
          o[0]=f2bf(acc[mt][nt][0]); o[1]=f2bf(acc[mt][nt][1]);
          o[2]=f2bf(acc[mt][nt][2]); o[3]=f2bf(acc[mt][nt][3]);
          *(u16x4*)(VT + ((size_t)(b*1024 + c))*Nl + n) = o;
        }
      }
    }
  }
}

// ---------------- MFMA flash attention, all levels merged, no-max online softmax ----
__global__ __launch_bounds__(256) void flash_k(const u16* __restrict__ QKVg,
                                               const u16* __restrict__ VTg,
                                               u16* __restrict__ Og) {
  __shared__ __align__(16) u16 Kt[2][64*64];
  __shared__ __align__(16) u16 Vt[2][64*64];
  __shared__ __align__(16) u16 Ps[4][32*68];
  const int tid = threadIdx.x, lane = tid & 63, wid = tid >> 6;
  const int quad = lane >> 4, c16 = lane & 15;
  const int id = blockIdx.x;
  int qt, bh, Nl, rowbase; size_t vtoff;
  if (id < 512)      { qt = 15 - (id >> 5);            bh = id & 31;  Nl = 2048; rowbase = 0;    vtoff = 0; }
  else if (id < 768) { int t2 = id - 512; qt = 7 - (t2 >> 5); bh = t2 & 31; Nl = 1024; rowbase = 4096; vtoff = 4194304; }
  else               { int t2 = id - 768; qt = 3 - (t2 >> 5); bh = t2 & 31; Nl = 512;  rowbase = 6144; vtoff = 6291456; }
  const int b = bh >> 4, h = bh & 15;
  const u16* QK = QKVg + ((size_t)(rowbase + b*Nl)) * 3072 + h*64;
  u16* Ow = Og + ((size_t)(rowbase + b*Nl)) * 1024 + h*64;
  const u16* VT = VTg + vtoff + ((size_t)b*1024 + h*64) * (size_t)Nl;

  const int q0r = qt*128 + wid*32;
  short8 bq[2][2];
  #pragma unroll
  for (int qh = 0; qh < 2; qh++) {
    const u16* qp = QK + (size_t)(q0r + qh*16 + c16)*3072 + quad*8;
    bq[qh][0] = *(const short8*)qp;
    bq[qh][1] = *(const short8*)(qp + 32);
  }
  const int si0 = wid*2, si1 = si0 + 1;
  const int sr0 = si0*8 + (lane>>3), sr1 = si1*8 + (lane>>3);
  const int sg  = ((lane&7) ^ (lane>>3)) * 8;
  const u16* Ks0 = QK + 1024 + (size_t)sr0*3072 + sg;
  const u16* Ks1 = QK + 1024 + (size_t)sr1*3072 + sg;
  const u16* Vs0 = VT + (size_t)sr0*Nl + sg;
  const u16* Vs1 = VT + (size_t)sr1*Nl + sg;

  f32x4 oacc[2][4];
  f32x4 lacc[2];
  #pragma unroll
  for (int qh = 0; qh < 2; qh++) {
    lacc[qh] = f32x4{0.f,0.f,0.f,0.f};
    #pragma unroll
    for (int nt = 0; nt < 4; nt++) oacc[qh][nt] = f32x4{0.f,0.f,0.f,0.f};
  }

  auto stage = [&](int kt, int p) {
    const size_t ko = (size_t)kt * 64;
    gload_lds16(Ks0 + ko*3072, &Kt[p][si0*512]);
    gload_lds16(Ks1 + ko*3072, &Kt[p][si1*512]);
    gload_lds16(Vs0 + ko,      &Vt[p][si0*512]);
    gload_lds16(Vs1 + ko,      &Vt[p][si1*512]);
  };
  const int kmax_w = 2*qt + (wid >> 1);
  const int ktot   = 2*qt + 2;
  stage(0, 0);

  for (int kt = 0; kt < ktot; kt++) {
    const int p = kt & 1;
    __syncthreads();
    if (kt + 1 < ktot) stage(kt+1, p^1);
    if (kt > kmax_w) continue;

    f32x4 st[2][4];
    #pragma unroll
    for (int nt = 0; nt < 4; nt++) {
      int key = nt*16 + c16, x = key & 7;
      short8 a0 = *(const short8*)(&Kt[p][key*64 + ((quad    ) ^ x)*8]);
      short8 a1 = *(const short8*)(&Kt[p][key*64 + ((quad + 4) ^ x)*8]);
      #pragma unroll
      for (int qh = 0; qh < 2; qh++) {
        f32x4 s = f32x4{0.f,0.f,0.f,0.f};
        s = __builtin_amdgcn_mfma_f32_16x16x32_bf16(a0, bq[qh][0], s, 0, 0, 0);
        s = __builtin_amdgcn_mfma_f32_16x16x32_bf16(a1, bq[qh][1], s, 0, 0, 0);
        st[qh][nt] = s;
      }
    }
    if (kt >= 2*qt) {
      const int kb = kt*64;
      #pragma unroll
      for (int qh = 0; qh < 2; qh++) {
        const int qr = q0r + qh*16 + c16;
        #pragma unroll
        for (int nt = 0; nt < 4; nt++) {
          #pragma unroll
          for (int r = 0; r < 4; r++) {
            float e = __builtin_amdgcn_exp2f(st[qh][nt][r]);
            st[qh][nt][r] = (kb + nt*16 + quad*4 + r <= qr) ? e : 0.f;
          }
          lacc[qh] += st[qh][nt];
        }
      }
    } else {
      #pragma unroll
      for (int qh = 0; qh < 2; qh++)
        #pragma unroll
        for (int nt = 0; nt < 4; nt++) {
          #pragma unroll
          for (int r = 0; r < 4; r++) st[qh][nt][r] = __builtin_amdgcn_exp2f(st[qh][nt][r]);
          lacc[qh] += st[qh][nt];
        }
    }
    #pragma unroll
    for (int qh = 0; qh < 2; qh++) {
      const int prow = qh*16 + c16;
      #pragma unroll
      for (int nt = 0; nt < 4; nt++) {
        uint2 pk;
        pk.x = pkbf(st[qh][nt][0], st[qh][nt][1]);
        pk.y = pkbf(st[qh][nt][2], st[qh][nt][3]);
        *(uint2*)(&Ps[wid][prow*68 + nt*16 + quad*4]) = pk;
      }
    }
    short8 bp[2][2];
    #pragma unroll
    for (int qh = 0; qh < 2; qh++) {
      bp[qh][0] = *(const short8*)(&Ps[wid][(qh*16 + c16)*68 +      quad*8]);
      bp[qh][1] = *(const short8*)(&Ps[wid][(qh*16 + c16)*68 + 32 + quad*8]);
    }
    #pragma unroll
    for (int nt = 0; nt < 4; nt++) {
      int dh = nt*16 + c16, x = dh & 7;
      short8 a0 = *(const short8*)(&Vt[p][dh*64 + ((quad    ) ^ x)*8]);
      short8 a1 = *(const short8*)(&Vt[p][dh*64 + ((quad + 4) ^ x)*8]);
      #pragma unroll
      for (int qh = 0; qh < 2; qh++) {
        oacc[qh][nt] = __builtin_amdgcn_mfma_f32_16x16x32_bf16(a0, bp[qh][0], oacc[qh][nt], 0, 0, 0);
        oacc[qh][nt] = __builtin_amdgcn_mfma_f32_16x16x32_bf16(a1, bp[qh][1], oacc[qh][nt], 0, 0, 0);
      }
    }
  }
  #pragma unroll
  for (int qh = 0; qh < 2; qh++) {
    float ls = lacc[qh][0] + lacc[qh][1] + lacc[qh][2] + lacc[qh][3];
    ls += __shfl_xor(ls, 16);
    ls += __shfl_xor(ls, 32);
    const float rl = 1.f / ls;
    #pragma unroll
    for (int nt = 0; nt < 4; nt++) {
      uint2 o;
      o.x = pkbf(oacc[qh][nt][0]*rl, oacc[qh][nt][1]*rl);
      o.y = pkbf(oacc[qh][nt][2]*rl, oacc[qh][nt][3]*rl);
      *(uint2*)(Ow + (size_t)(q0r + qh*16 + c16)*1024 + nt*16 + quad*4) = o;
    }
  }
}

// ---------------- Gram matrix over repeat map (bf16 Y), 4-wide ----------------
__global__ __launch_bounds__(256) void gram_k(const u16* __restrict__ Y0, const u16* __restrict__ Y1,
                                              const u16* __restrict__ Y2, float* __restrict__ G) {
  float a[6] = {0,0,0,0,0,0};
  const int total4 = CNT/4;
  for (int i = blockIdx.x*256 + threadIdx.x; i < total4; i += gridDim.x*256) {
    int d4 = i & 255; int n = (i >> 8) & (N_-1); int b = i >> 19;
    u16x4 y0v = *(const u16x4*)(Y0 + (size_t)i*4);
    u16x4 y1v = *(const u16x4*)(Y1 + (((size_t)(b*1024 + (n>>1))) << 10) + d4*4);
    u16x4 y2v = *(const u16x4*)(Y2 + (((size_t)(b*512  + (n>>2))) << 10) + d4*4);
    #pragma unroll
    for (int t = 0; t < 4; t++) {
      float y0 = bf2f(y0v[t]), y1 = bf2f(y1v[t]), y2 = bf2f(y2v[t]);
      a[0] += y0*y0; a[1] += y0*y1; a[2] += y0*y2;
      a[3] += y1*y1; a[4] += y1*y2; a[5] += y2*y2;
    }
  }
  __shared__ float red[4][6];
  const int lane = threadIdx.x & 63, wid = threadIdx.x >> 6;
  #pragma unroll
  for (int t = 0; t < 6; t++) {
    float v = a[t];
    v += __shfl_xor(v, 1);  v += __shfl_xor(v, 2);  v += __shfl_xor(v, 4);
    v += __shfl_xor(v, 8);  v += __shfl_xor(v, 16); v += __shfl_xor(v, 32);
    a[t] = v;
  }
  if (lane == 0)
    #pragma unroll
    for (int t = 0; t < 6; t++) red[wid][t] = a[t];
  __syncthreads();
  if (threadIdx.x < 6)
    atomicAdd(&G[threadIdx.x], red[0][threadIdx.x] + red[1][threadIdx.x] +
                               red[2][threadIdx.x] + red[3][threadIdx.x]);
}

// ---------------- Nash iterations + aux loss + both Sinkhorns (scalar) ----------------
__global__ void head_k(float* SC, const float* __restrict__ agg, const float* __restrict__ mA,
                       const float* __restrict__ mF, float* __restrict__ aux_out) {
  if (threadIdx.x != 0 || blockIdx.x != 0) return;
  float G[6];
  for (int t = 0; t < 6; t++) G[t] = SC[t];
  const int gi[3][3] = {{0,1,2},{1,3,4},{2,4,5}};
  float a[3] = {agg[0], agg[1], agg[2]};
  float w[3];
  {
    float m = fmaxf(a[0], fmaxf(a[1], a[2])); float s = 0.f;
    for (int l = 0; l < 3; l++) { w[l] = expf(a[l]-m); s += w[l]; }
    for (int l = 0; l < 3; l++) w[l] /= s;
  }
  const float inv = 1.f / (float)CNT;
  for (int it = 0; it < 3; it++) {
    float q = 0.f;
    for (int l = 0; l < 3; l++) for (int m2 = 0; m2 < 3; m2++) q += w[l]*w[m2]*G[gi[l][m2]];
    float z[3];
    for (int l = 0; l < 3; l++) {
      float dot = w[0]*G[gi[l][0]] + w[1]*G[gi[l][1]] + w[2]*G[gi[l][2]];
      z[l] = a[l] - (G[gi[l][l]] - 2.f*dot + q) * inv;
    }
    float m = fmaxf(z[0], fmaxf(z[1], z[2])); float s = 0.f;
    for (int l = 0; l < 3; l++) { w[l] = expf(z[l]-m); s += w[l]; }
    for (int l = 0; l < 3; l++) w[l] /= s;
  }
  SC[6] = w[0]; SC[7] = w[1]; SC[8] = w[2];
  aux_out[0] = w[0]*logf(w[0]*3.f + 1e-9f) + w[1]*logf(w[1]*3.f + 1e-9f) + w[2]*logf(w[2]*3.f + 1e-9f);
  for (int which = 0; which < 2; which++) {
    const float* Lg = which ? mF : mA;
    float M0 = expf(Lg[0]), M1 = expf(Lg[1]), M2 = expf(Lg[2]), M3 = expf(Lg[3]);
    for (int i2 = 0; i2 < 10; i2++) {
      float r0 = M0+M1, r1 = M2+M3; M0 /= r0; M1 /= r0; M2 /= r1; M3 /= r1;
      float c0 = M0+M2, c1 = M1+M3; M0 /= c0; M2 /= c0; M1 /= c1; M3 /= c1;
    }
    SC[9 + which*2] = M0; SC[10 + which*2] = M1;
  }
}

// ---------------- fused mix1 + FFN RMSNorm: one row per block ----------------
__global__ __launch_bounds__(256) void mixrms_k(const float* __restrict__ x, const u16* __restrict__ Y0,
                                                const u16* __restrict__ Y1, const u16* __restrict__ Y2,
                                                const float* __restrict__ SC, const float* __restrict__ w2,
                                                float* __restrict__ x1, u16* __restrict__ xn2) {
  const float w0 = SC[6], w1 = SC[7], ww2 = SC[8], p0 = SC[9], p1 = SC[10];
  const int i = blockIdx.x;
  const int b = i >> 11, n = i & 2047;
  const float* xr = x + (size_t)i * D_;
  const u16* y0 = Y0 + (size_t)i * D_;
  const u16* y1 = Y1 + (size_t)(b*1024 + (n>>1)) * D_;
  const u16* y2 = Y2 + (size_t)(b*512  + (n>>2)) * D_;
  float xv[4], wv[4];
  float ss = 0.f;
  #pragma unroll
  for (int t = 0; t < 4; t++) {
    int c = threadIdx.x + t*256;
    float v = p0*xr[c] + p1*(w0*bf2f(y0[c]) + w1*bf2f(y1[c]) + ww2*bf2f(y2[c]));
    xv[t] = v; wv[t] = w2[c]; ss += v*v;
    x1[(size_t)i*D_ + c] = v;
  }
  #pragma unroll
  for (int o = 1; o < 64; o <<= 1) ss += __shfl_xor(ss, o);
  __shared__ float red[4];
  if ((threadIdx.x & 63) == 0) red[threadIdx.x >> 6] = ss;
  __syncthreads();
  float sc = rsqrtf((red[0]+red[1]+red[2]+red[3]) * (1.f/D_) + 1e-6f);
  #pragma unroll
  for (int t = 0; t < 4; t++) {
    int c = threadIdx.x + t*256;
    xn2[(size_t)i*D_ + c] = f2bf(xv[t]*wv[t]*sc);
  }
}

// ================================ host launcher ================================
extern "C" void kernel_launch(void* const* d_in, const int* in_sizes, int n_in,
                              void* d_out, int out_size, void* d_ws, size_t ws_size,
                              hipStream_t stream) {
  (void)in_sizes; (void)n_in; (void)out_size; (void)ws_size;
  const float* x    = (const float*)d_in[0];
  const float* nw1  = (const float*)d_in[1];
  const float* nw2  = (const float*)d_in[2];
  const float* Wdec = (const float*)d_in[3];
  const float* Wq   = (const float*)d_in[4];
  const float* Wk   = (const float*)d_in[5];
  const float* Wv   = (const float*)d_in[6];
  const float* Wo   = (const float*)d_in[7];
  const float* agg  = (const float*)d_in[8];
  const float* Wg   = (const float*)d_in[9];
  const float* Wu   = (const float*)d_in[10];
  const float* Wdn  = (const float*)d_in[11];
  const float* mA   = (const float*)d_in[12];
  const float* mF   = (const float*)d_in[13];
  float* out = (float*)d_out;

  char* ws = (char*)d_ws;
  size_t off = 0;
  auto take = [&](size_t b) { size_t r = off; off += (b + 255) & ~(size_t)255; return r; };

  u16* A_wp  = (u16*)(ws + take((size_t)9216*1024*2));
  u16* WdecB = (u16*)(ws + take((size_t)3*1024*1024*2));
  u16* Wqkv  = (u16*)(ws + take((size_t)9216*1024*2));
  u16* BTgu  = (u16*)(ws + take((size_t)5632*1024*2));   // gate/up 16-col interleaved
  u16* WdnT  = (u16*)(ws + take((size_t)HIDP*1024*2));
  u16* WoT   = (u16*)(ws + take((size_t)1024*1024*2));
  u16* xn_all = (u16*)(ws + take((size_t)7168*1024*2));
  float* x1  = (float*)(ws + take((size_t)CNT*4));
  float* SCb = (float*)(ws + take(256));
  char*  big = ws + take(88080384);
  // attention phase
  u16*   QKV   = (u16*)big;                              // [7168, 3072] bf16 (V cols unused)
  u16*   VTa   = (u16*)(big + 44040192);                 // per-level [b][1024][Nl]
  u16*   Ob    = (u16*)(big + 58720256);                 // [7168, 1024] bf16
  u16*   YC    = (u16*)(big + 73400320);                 // [7168, 1024] bf16
  // FFN phase alias (attention working set dead by then; YC region untouched)
  u16*   hbuf  = (u16*)big;                              // [4096, 2816] bf16

  dim3 blk(256);
  const int BIG = 1 << 30;

  // ---- 1: all weight prep in one launch (+ SCb zero + BTgu pad zero) ----
  wprep_k<<<21924, blk, 0, stream>>>(Wdec, Wq, Wk, Wv, Wo, Wg, Wu, Wdn,
                                     A_wp, WdecB, WoT, BTgu, WdnT, SCb);
  // ---- 2: fused QKV weights: F_l^T = [Wq|Wk|Wv]_l^T x Wdec_l^T ----
  gemm_t<8,1><<<dim3(8, 36), blk, 0, stream>>>(A_wp, WdecB, Wqkv, nullptr, nullptr, nullptr,
                                               1024, 1024, 12, 24, 1024u*1024u);
  // ---- 3-4: attention RMSNorm (+pool1 fused), pool2 ----
  rmsA_k<<<2048, blk, 0, stream>>>(x, nw1, xn_all, xn_all + (size_t)4096*1024);
  pool_k<<<512, blk, 0, stream>>>(xn_all + (size_t)4096*1024, xn_all + (size_t)6144*1024, 9);
  // ---- 5: QKV GEMM (per-level weight select) + fused V transpose epilogue ----
  gemm_t<8,4><<<dim3(24, 28), blk, 0, stream>>>(xn_all, Wqkv, QKV, VTa, nullptr, nullptr,
                                                3072, 1024, 16, 24, 3072u*1024u);
  // ---- 6: flash attention (all levels) ----
  flash_k<<<896, blk, 0, stream>>>(QKV, VTa, Ob);
  // ---- 7: output projection -> YC (bf16) ----
  gemm_t<8,1><<<dim3(8, 28), blk, 0, stream>>>(Ob, WoT, YC, nullptr, nullptr, nullptr,
                                               1024, 1024, BIG, BIG, 0u);
  // ---- 8-9: Nash via Gram + scalar head ----
  u16* YC1 = YC + (size_t)4096*1024;
  u16* YC2 = YC + (size_t)6144*1024;
  gram_k<<<1024, blk, 0, stream>>>(YC, YC1, YC2, SCb);
  head_k<<<1, 64, 0, stream>>>(SCb, agg, mA, mF, out + CNT);
  // ---- 10: mix1 + FFN RMSNorm fused ----
  mixrms_k<<<4096, blk, 0, stream>>>(x, YC, YC1, YC2, SCb, nw2, x1, xn_all);
  // ---- 11: gate/up GEMM with fused silu*mul epilogue ----
  gemm_t<8,3><<<dim3(44, 16), blk, 0, stream>>>(xn_all, BTgu, hbuf, nullptr, nullptr, nullptr,
                                                5632, 1024, BIG, BIG, 0u);
  // ---- 12: down GEMM with fused final residual mix ----
  gemm_t<4,2><<<dim3(8, 32), blk, 0, stream>>>(hbuf, WdnT, out, nullptr, x1, SCb,
                                               1024, HIDP, BIG, BIG, 0u);
}

// Round 2
// 492.961 us; speedup vs baseline: 1.0207x; 1.0124x over previous
//
#include <hip/hip_runtime.h>
#include <stdint.h>

// MAHA decoder block, MI355X/gfx950. Round 7: 2-phase prefetch GEMM —
// double-buffered LDS, stage(t+1) issued before compute(t), one barrier/K-step.
// MT=4 (128x128 tile), BK=64, 64KB LDS -> 2 blocks/CU.
// B=2, N=2048, D=1024, H=16(dh=64), L=3, R=2, HID=2734(->2816), fp32 I/O.

#define B_   2
#define N_   2048
#define D_   1024
#define H_   16
#define DH_  64
#define HID_ 2734
#define HIDP 2816
#define CNT  (B_*N_*D_)   // 4194304
#define LOG2E 1.4426950408889634f

typedef unsigned short u16;
typedef __attribute__((ext_vector_type(8))) short short8;
typedef __attribute__((ext_vector_type(4))) float f32x4;
typedef __attribute__((ext_vector_type(4))) uint16_t u16x4;

__device__ __forceinline__ u16 f2bf(float f) {
  uint32_t u = __builtin_bit_cast(uint32_t, f);
  u += 0x7fffu + ((u >> 16) & 1u);          // RNE
  return (u16)(u >> 16);
}
__device__ __forceinline__ float bf2f(u16 h) {
  uint32_t u = ((uint32_t)h) << 16;
  return __builtin_bit_cast(float, u);
}
__device__ __forceinline__ uint32_t pkbf(float a, float b) {
  return (uint32_t)f2bf(a) | ((uint32_t)f2bf(b) << 16);
}
__device__ __forceinline__ void gload_lds16(const void* g, void* l) {
  __builtin_amdgcn_global_load_lds(
      (const __attribute__((address_space(1))) uint32_t*)g,
      (__attribute__((address_space(3))) uint32_t*)l, 16, 0, 0);
}

// ============ batched weight prep: all fp32->bf16 transposes + Wdec convert + SC zero ====
// blocks: [0,9216) QKV weight transposes | [9216,10240) Wo | [10240,13056) Wg(gate-ilv)
// [13056,15872) Wu(up-ilv) | [15872,18688) Wdn | [18688,21760) Wdec plain convert
// [21760,21924) BTgu pad-row zero-fill (rows 5454,5455,5470..5631)
__global__ __launch_bounds__(256) void wprep_k(const float* __restrict__ Wdec, const float* __restrict__ Wq,
                                               const float* __restrict__ Wk, const float* __restrict__ Wv,
                                               const float* __restrict__ Wo, const float* __restrict__ Wg,
                                               const float* __restrict__ Wu, const float* __restrict__ Wdn,
                                               u16* __restrict__ A_wp, u16* __restrict__ WdecB,
                                               u16* __restrict__ WoT, u16* __restrict__ BTgu,
                                               u16* __restrict__ WdnT, float* __restrict__ SCb) {
  const int bid = blockIdx.x;
  if (bid >= 21760) {
    int bid0 = bid - 21760;
    int row = (bid0 < 2) ? (5454 + bid0) : (5470 + (bid0 - 2));
    u16x4 zz; zz[0]=0; zz[1]=0; zz[2]=0; zz[3]=0;
    *(u16x4*)(BTgu + (size_t)row*1024 + threadIdx.x*4) = zz;
    return;
  }
  if (bid >= 18688) {
    if (bid == 18688 && threadIdx.x < 64) SCb[threadIdx.x] = 0.f;
    int i = (bid - 18688)*1024 + threadIdx.x*4;
    float4 v = *(const float4*)(Wdec + i);
    u16x4 o; o[0]=f2bf(v.x); o[1]=f2bf(v.y); o[2]=f2bf(v.z); o[3]=f2bf(v.w);
    *(u16x4*)(WdecB + i) = o;
    return;
  }
  const float* src; u16* dst; int K, N, KP; float scale; int imode; int bx, by;
  if (bid < 9216) {
    int j = bid >> 10, t = bid & 1023; bx = t & 31; by = t >> 5;
    int l = j / 3, which = j - l*3;
    src = which==0 ? Wq + (size_t)l*1048576 : which==1 ? Wk + (size_t)l*1048576 : Wv;
    dst = A_wp + (size_t)(l*3072 + which*1024)*1024;
    K = 1024; N = 1024; KP = 1024; scale = (which==0) ? 0.125f*LOG2E : 1.f; imode = 0;
  } else if (bid < 10240) {
    int t = bid - 9216; bx = t & 31; by = t >> 5;
    src = Wo; dst = WoT; K=1024; N=1024; KP=1024; scale=1.f; imode=0;
  } else if (bid < 13056) {
    int t = bid - 10240; bx = t % 88; by = t / 88;
    src = Wg; dst = BTgu; K=1024; N=HID_; KP=1024; scale=1.f; imode=1;
  } else if (bid < 15872) {
    int t = bid - 13056; bx = t % 88; by = t / 88;
    src = Wu; dst = BTgu; K=1024; N=HID_; KP=1024; scale=1.f; imode=2;
  } else {
    int t = bid - 15872; bx = t & 31; by = t >> 5;
    src = Wdn; dst = WdnT; K=HID_; N=1024; KP=HIDP; scale=1.f; imode=0;
  }
  __shared__ float tt[32][33];
  const int tx = threadIdx.x & 31, ty = threadIdx.x >> 5;
  const int nb = bx*32, kb = by*32;
  #pragma unroll
  for (int i = 0; i < 4; i++) {
    int k = kb + ty + i*8, n = nb + tx;
    tt[ty + i*8][tx] = (k < K && n < N) ? src[(size_t)k * N + n] * scale : 0.f;
  }
  __syncthreads();
  #pragma unroll
  for (int i = 0; i < 4; i++) {
    int n = nb + ty + i*8, k = kb + tx;
    int r;
    if (imode == 0) r = n;
    else if (imode == 1) r = ((n>>4)<<5) + (n&15);
    else r = ((n>>4)<<5) + 16 + (n&15);
    dst[(size_t)r * KP + k] = f2bf(tt[tx][ty + i*8]);
  }
}

// ---------------- attention RMSNorm: 2 rows per block + fp32 pooled row ----------------
__global__ __launch_bounds__(256) void rmsA_k(const float* __restrict__ x, const float* __restrict__ w,
                                              u16* __restrict__ xn, u16* __restrict__ xp1) {
  const int j = blockIdx.x;
  const float* xr0 = x + (size_t)(2*j) * D_;
  const float* xr1 = xr0 + D_;
  float a0[4], a1[4], wv[4];
  float ss0 = 0.f, ss1 = 0.f;
  #pragma unroll
  for (int i = 0; i < 4; i++) {
    int c = threadIdx.x + i*256;
    a0[i] = xr0[c]; a1[i] = xr1[c]; wv[i] = w[c];
    ss0 += a0[i]*a0[i]; ss1 += a1[i]*a1[i];
  }
  #pragma unroll
  for (int o = 1; o < 64; o <<= 1) { ss0 += __shfl_xor(ss0, o); ss1 += __shfl_xor(ss1, o); }
  __shared__ float r0[4], r1[4];
  if ((threadIdx.x & 63) == 0) { r0[threadIdx.x >> 6] = ss0; r1[threadIdx.x >> 6] = ss1; }
  __syncthreads();
  float sc0 = rsqrtf((r0[0]+r0[1]+r0[2]+r0[3]) * (1.f/D_) + 1e-6f);
  float sc1 = rsqrtf((r1[0]+r1[1]+r1[2]+r1[3]) * (1.f/D_) + 1e-6f);
  #pragma unroll
  for (int i = 0; i < 4; i++) {
    int c = threadIdx.x + i*256;
    float xa = a0[i]*wv[i]*sc0, xb = a1[i]*wv[i]*sc1;
    xn[(size_t)(2*j)*D_ + c]     = f2bf(xa);
    xn[(size_t)(2*j)*D_ + D_ + c] = f2bf(xb);
    xp1[(size_t)j*D_ + c] = f2bf(0.5f*(xa + xb));
  }
}

// ---------------- avg-pool by 2 along seq (bf16), 4-wide; No = 1<<lg ----------------
__global__ __launch_bounds__(256) void pool_k(const u16* __restrict__ in, u16* __restrict__ out, int lg) {
  const int No = 1 << lg;
  const int total4 = B_ * No * 256;
  for (int i = blockIdx.x*256 + threadIdx.x; i < total4; i += gridDim.x*256) {
    int d4 = i & 255; int j = (i >> 8) & (No - 1); int b = i >> (8 + lg);
    size_t src = ((size_t)(b*2*No + 2*j) << 10) + d4*4;
    u16x4 a = *(const u16x4*)(in + src);
    u16x4 c = *(const u16x4*)(in + src + 1024);
    u16x4 o;
    #pragma unroll
    for (int t = 0; t < 4; t++) o[t] = f2bf(0.5f * (bf2f(a[t]) + bf2f(c[t])));
    *(u16x4*)(out + (size_t)i*4) = o;
  }
}

// ---------------- MFMA GEMM, C = A[M,K] * BT[N,K]^T; block = MT*32 x 128, BK=64 ----
// 2-phase prefetch: double-buffered LDS, stage(t+1) issued before compute(t),
// one __syncthreads per K-step (compiler emits vmcnt(0)+lgkmcnt(0) before s_barrier).
// MODE 1: bf16 store. MODE 2: fp32 out = SCp[11]*X1 + SCp[12]*acc. MODE 3: silu(gate)*up
// epilogue (BT interleaved at 16-col granularity), bf16 h store with row stride HIDP.
// MODE 4: QKV epilogue: cols<2048 bf16 store (stride N); cols>=2048 V stored transposed
// into Cv2 (per-level [b][c][n] layout), V not written to C.
template<int MT, int MODE>
__global__ __launch_bounds__(256, 2) void gemm_t(const u16* __restrict__ A, const u16* __restrict__ BT,
                                                 void* __restrict__ Cv, void* __restrict__ Cv2,
                                                 const float* __restrict__ X1,
                                                 const float* __restrict__ SCp,
                                                 int N, int K, int t1, int t2, unsigned int bt_stride) {
  __shared__ __align__(16) u16 As[2][MT*32*64];
  __shared__ __align__(16) u16 Bs[2][128*64];
  const int tid = threadIdx.x;
  const int lane = tid & 63, wid = tid >> 6;
  const int quad = lane >> 4, c16 = lane & 15;
  const int y = blockIdx.y;
  const int m0 = y * (MT*32), n0 = blockIdx.x * 128;
  const int wm = wid >> 1, wn = wid & 1;
  const int level = (y >= t2) ? 2 : ((y >= t1) ? 1 : 0);
  BT += (size_t)level * bt_stride;

  f32x4 acc[MT][4];
  #pragma unroll
  for (int i = 0; i < MT; i++)
    #pragma unroll
    for (int j = 0; j < 4; j++) acc[i][j] = f32x4{0.f,0.f,0.f,0.f};

  // staging: 1KB wave-chunks of 8 rows x 64 cols; source pre-swizzled so that the
  // swizzled read (chunk ^ (row&7)) is bank-spread (2 lanes/bank).
  const int srow = lane >> 3;         // row within chunk
  const int schunk = lane & 7;        // 8-elem (16B) chunk within 64-col row
  auto stage = [&](int k0, int p) {
    #pragma unroll
    for (int t = 0; t < MT; t++) {
      int idx = wid*MT + t;
      int row = idx*8 + srow;
      int g = (schunk ^ (row & 7)) * 8;
      gload_lds16(A + (size_t)(m0+row)*K + k0 + g, &As[p][idx*512]);
    }
    #pragma unroll
    for (int t = 0; t < 4; t++) {
      int idx = wid*4 + t;
      int row = idx*8 + srow;
      int g = (schunk ^ (row & 7)) * 8;
      gload_lds16(BT + (size_t)(n0+row)*K + k0 + g, &Bs[p][idx*512]);
    }
  };

  const int nk = K >> 6;
  stage(0, 0);
  __syncthreads();                    // buf0 staged (vmcnt(0) drained by compiler)
  for (int ki = 0; ki < nk; ki++) {
    const int p = ki & 1;
    if (ki + 1 < nk) stage((ki + 1) << 6, p ^ 1);   // prefetch next tile (in flight
                                                     // across this step's compute)
    #pragma unroll
    for (int kh = 0; kh < 2; kh++) {
      short8 af[MT], bfr[4];
      #pragma unroll
      for (int mt = 0; mt < MT; mt++) {
        int ar = wm*(MT*16) + mt*16 + c16;
        int ck = (kh*4 + quad) ^ (ar & 7);
        af[mt] = *(const short8*)(&As[p][ar*64 + ck*8]);
      }
      #pragma unroll
      for (int nt = 0; nt < 4; nt++) {
        int br = wn*64 + nt*16 + c16;
        int ck = (kh*4 + quad) ^ (br & 7);
        bfr[nt] = *(const short8*)(&Bs[p][br*64 + ck*8]);
      }
      #pragma unroll
      for (int mt = 0; mt < MT; mt++)
        #pragma unroll
        for (int nt = 0; nt < 4; nt++)
          acc[mt][nt] = __builtin_amdgcn_mfma_f32_16x16x32_bf16(af[mt], bfr[nt], acc[mt][nt], 0, 0, 0);
    }
    __syncthreads();                  // next buffer staged; this buffer free
  }
  if (MODE == 1) {
    u16* C = (u16*)Cv;
    #pragma unroll
    for (int mt = 0; mt < MT; mt++)
      #pragma unroll
      for (int nt = 0; nt < 4; nt++)
        #pragma unroll
        for (int r = 0; r < 4; r++) {
          int row = m0 + wm*(MT*16) + mt*16 + quad*4 + r;
          int col = n0 + wn*64 + nt*16 + c16;
          C[(size_t)row * N + col] = f2bf(acc[mt][nt][r]);
        }
  } else if (MODE == 2) {
    float* C = (float*)Cv;
    const float q0 = SCp[11], q1 = SCp[12];
    #pragma unroll
    for (int mt = 0; mt < MT; mt++)
      #pragma unroll
      for (int nt = 0; nt < 4; nt++)
        #pragma unroll
        for (int r = 0; r < 4; r++) {
          int row = m0 + wm*(MT*16) + mt*16 + quad*4 + r;
          int col = n0 + wn*64 + nt*16 + c16;
          size_t o = (size_t)row * N + col;
          C[o] = q0 * X1[o] + q1 * acc[mt][nt][r];
        }
  } else if (MODE == 3) {
    u16* Hc = (u16*)Cv;
    const int hbase = (n0 >> 1) + wn*32;
    #pragma unroll
    for (int mt = 0; mt < MT; mt++)
      #pragma unroll
      for (int r = 0; r < 4; r++) {
        int row = m0 + wm*(MT*16) + mt*16 + quad*4 + r;
        #pragma unroll
        for (int pr = 0; pr < 2; pr++) {
          float g = acc[mt][2*pr][r], u = acc[mt][2*pr+1][r];
          float h = g / (1.f + __expf(-g)) * u;
          Hc[(size_t)row * HIDP + hbase + pr*16 + c16] = f2bf(h);
        }
      }
  } else {  // MODE 4
    if (n0 < 2048) {
      u16* C = (u16*)Cv;
      #pragma unroll
      for (int mt = 0; mt < MT; mt++)
        #pragma unroll
        for (int nt = 0; nt < 4; nt++)
          #pragma unroll
          for (int r = 0; r < 4; r++) {
            int row = m0 + wm*(MT*16) + mt*16 + quad*4 + r;
            int col = n0 + wn*64 + nt*16 + c16;
            C[(size_t)row * N + col] = f2bf(acc[mt][nt][r]);
          }
    } else {
      const int Nl = 2048 >> level;
      const int lvbase = (level==0) ? 0 : (level==1) ? 4096 : 6144;
      const size_t vtoff = (level==0) ? 0 : (level==1) ? 4194304 : 6291456;
      u16* VT = (u16*)Cv2 + vtoff;
      #pragma unroll
      for (int mt = 0; mt < MT; mt++) {
        int rowg = m0 + wm*(MT*16) + mt*16 + quad*4;   // r=0 row; +3 stays in-row-group
        int nloc = rowg - lvbase;
        int b = nloc / Nl;              // Nl is power of two
        int n = nloc - b*Nl;
        #pragma unroll
        for (int nt = 0; nt < 4; nt++) {
          int c = n0 - 2048 + wn*64 + nt*16 + c16;
          u16x4 o;
          o[0]=f2bf(acc[mt][nt][0]); o[1]=f2bf(acc[mt][nt][1]);
          o[2]=f2bf(acc[mt][nt][2]); o[3]=f2bf(acc[mt][nt][3]);
          *(u16x4*)(VT + ((size_t)(b*1024 + c))*Nl + n) = o;
        }
      }
    }
  }
}

// ---------------- MFMA flash attention, all levels merged, no-max online softmax ----
__global__ __launch_bounds__(256) void flash_k(const u16* __restrict__ QKVg,
                                               const u16* __restrict__ VTg,
                                               u16* __restrict__ Og) {
  __shared__ __align__(16) u16 Kt[2][64*64];
  __shared__ __align__(16) u16 Vt[2][64*64];
  __shared__ __align__(16) u16 Ps[4][32*68];
  const int tid = threadIdx.x, lane = tid & 63, wid = tid >> 6;
  const int quad = lane >> 4, c16 = lane & 15;
  const int id = blockIdx.x;
  int qt, bh, Nl, rowbase; size_t vtoff;
  if (id < 512)      { qt = 15 - (id >> 5);            bh = id & 31;  Nl = 2048; rowbase = 0;    vtoff = 0; }
  else if (id < 768) { int t2 = id - 512; qt = 7 - (t2 >> 5); bh = t2 & 31; Nl = 1024; rowbase = 4096; vtoff = 4194304; }
  else               { int t2 = id - 768; qt = 3 - (t2 >> 5); bh = t2 & 31; Nl = 512;  rowbase = 6144; vtoff = 6291456; }
  const int b = bh >> 4, h = bh & 15;
  const u16* QK = QKVg + ((size_t)(rowbase + b*Nl)) * 3072 + h*64;
  u16* Ow = Og + ((size_t)(rowbase + b*Nl)) * 1024 + h*64;
  const u16* VT = VTg + vtoff + ((size_t)b*1024 + h*64) * (size_t)Nl;

  const int q0r = qt*128 + wid*32;
  short8 bq[2][2];
  #pragma unroll
  for (int qh = 0; qh < 2; qh++) {
    const u16* qp = QK + (size_t)(q0r + qh*16 + c16)*3072 + quad*8;
    bq[qh][0] = *(const short8*)qp;
    bq[qh][1] = *(const short8*)(qp + 32);
  }
  const int si0 = wid*2, si1 = si0 + 1;
  const int sr0 = si0*8 + (lane>>3), sr1 = si1*8 + (lane>>3);
  const int sg  = ((lane&7) ^ (lane>>3)) * 8;
  const u16* Ks0 = QK + 1024 + (size_t)sr0*3072 + sg;
  const u16* Ks1 = QK + 1024 + (size_t)sr1*3072 + sg;
  const u16* Vs0 = VT + (size_t)sr0*Nl + sg;
  const u16* Vs1 = VT + (size_t)sr1*Nl + sg;

  f32x4 oacc[2][4];
  f32x4 lacc[2];
  #pragma unroll
  for (int qh = 0; qh < 2; qh++) {
    lacc[qh] = f32x4{0.f,0.f,0.f,0.f};
    #pragma unroll
    for (int nt = 0; nt < 4; nt++) oacc[qh][nt] = f32x4{0.f,0.f,0.f,0.f};
  }

  auto stage = [&](int kt, int p) {
    const size_t ko = (size_t)kt * 64;
    gload_lds16(Ks0 + ko*3072, &Kt[p][si0*512]);
    gload_lds16(Ks1 + ko*3072, &Kt[p][si1*512]);
    gload_lds16(Vs0 + ko,      &Vt[p][si0*512]);
    gload_lds16(Vs1 + ko,      &Vt[p][si1*512]);
  };
  const int kmax_w = 2*qt + (wid >> 1);
  const int ktot   = 2*qt + 2;
  stage(0, 0);

  for (int kt = 0; kt < ktot; kt++) {
    const int p = kt & 1;
    __syncthreads();
    if (kt + 1 < ktot) stage(kt+1, p^1);
    if (kt > kmax_w) continue;

    f32x4 st[2][4];
    #pragma unroll
    for (int nt = 0; nt < 4; nt++) {
      int key = nt*16 + c16, x = key & 7;
      short8 a0 = *(const short8*)(&Kt[p][key*64 + ((quad    ) ^ x)*8]);
      short8 a1 = *(const short8*)(&Kt[p][key*64 + ((quad + 4) ^ x)*8]);
      #pragma unroll
      for (int qh = 0; qh < 2; qh++) {
        f32x4 s = f32x4{0.f,0.f,0.f,0.f};
        s = __builtin_amdgcn_mfma_f32_16x16x32_bf16(a0, bq[qh][0], s, 0, 0, 0);
        s = __builtin_amdgcn_mfma_f32_16x16x32_bf16(a1, bq[qh][1], s, 0, 0, 0);
        st[qh][nt] = s;
      }
    }
    if (kt >= 2*qt) {
      const int kb = kt*64;
      #pragma unroll
      for (int qh = 0; qh < 2; qh++) {
        const int qr = q0r + qh*16 + c16;
        #pragma unroll
        for (int nt = 0; nt < 4; nt++) {
          #pragma unroll
          for (int r = 0; r < 4; r++) {
            float e = __builtin_amdgcn_exp2f(st[qh][nt][r]);
            st[qh][nt][r] = (kb + nt*16 + quad*4 + r <= qr) ? e : 0.f;
          }
          lacc[qh] += st[qh][nt];
        }
      }
    } else {
      #pragma unroll
      for (int qh = 0; qh < 2; qh++)
        #pragma unroll
        for (int nt = 0; nt < 4; nt++) {
          #pragma unroll
          for (int r = 0; r < 4; r++) st[qh][nt][r] = __builtin_amdgcn_exp2f(st[qh][nt][r]);
          lacc[qh] += st[qh][nt];
        }
    }
    #pragma unroll
    for (int qh = 0; qh < 2; qh++) {
      const int prow = qh*16 + c16;
      #pragma unroll
      for (int nt = 0; nt < 4; nt++) {
        uint2 pk;
        pk.x = pkbf(st[qh][nt][0], st[qh][nt][1]);
        pk.y = pkbf(st[qh][nt][2], st[qh][nt][3]);
        *(uint2*)(&Ps[wid][prow*68 + nt*16 + quad*4]) = pk;
      }
    }
    short8 bp[2][2];
    #pragma unroll
    for (int qh = 0; qh < 2; qh++) {
      bp[qh][0] = *(const short8*)(&Ps[wid][(qh*16 + c16)*68 +      quad*8]);
      bp[qh][1] = *(const short8*)(&Ps[wid][(qh*16 + c16)*68 + 32 + quad*8]);
    }
    #pragma unroll
    for (int nt = 0; nt < 4; nt++) {
      int dh = nt*16 + c16, x = dh & 7;
      short8 a0 = *(const short8*)(&Vt[p][dh*64 + ((quad    ) ^ x)*8]);
      short8 a1 = *(const short8*)(&Vt[p][dh*64 + ((quad + 4) ^ x)*8]);
      #pragma unroll
      for (int qh = 0; qh < 2; qh++) {
        oacc[qh][nt] = __builtin_amdgcn_mfma_f32_16x16x32_bf16(a0, bp[qh][0], oacc[qh][nt], 0, 0, 0);
        oacc[qh][nt] = __builtin_amdgcn_mfma_f32_16x16x32_bf16(a1, bp[qh][1], oacc[qh][nt], 0, 0, 0);
      }
    }
  }
  #pragma unroll
  for (int qh = 0; qh < 2; qh++) {
    float ls = lacc[qh][0] + lacc[qh][1] + lacc[qh][2] + lacc[qh][3];
    ls += __shfl_xor(ls, 16);
    ls += __shfl_xor(ls, 32);
    const float rl = 1.f / ls;
    #pragma unroll
    for (int nt = 0; nt < 4; nt++) {
      uint2 o;
      o.x = pkbf(oacc[qh][nt][0]*rl, oacc[qh][nt][1]*rl);
      o.y = pkbf(oacc[qh][nt][2]*rl, oacc[qh][nt][3]*rl);
      *(uint2*)(Ow + (size_t)(q0r + qh*16 + c16)*1024 + nt*16 + quad*4) = o;
    }
  }
}

// ---------------- Gram matrix over repeat map (bf16 Y), 4-wide ----------------
__global__ __launch_bounds__(256) void gram_k(const u16* __restrict__ Y0, const u16* __restrict__ Y1,
                                              const u16* __restrict__ Y2, float* __restrict__ G) {
  float a[6] = {0,0,0,0,0,0};
  const int total4 = CNT/4;
  for (int i = blockIdx.x*256 + threadIdx.x; i < total4; i += gridDim.x*256) {
    int d4 = i & 255; int n = (i >> 8) & (N_-1); int b = i >> 19;
    u16x4 y0v = *(const u16x4*)(Y0 + (size_t)i*4);
    u16x4 y1v = *(const u16x4*)(Y1 + (((size_t)(b*1024 + (n>>1))) << 10) + d4*4);
    u16x4 y2v = *(const u16x4*)(Y2 + (((size_t)(b*512  + (n>>2))) << 10) + d4*4);
    #pragma unroll
    for (int t = 0; t < 4; t++) {
      float y0 = bf2f(y0v[t]), y1 = bf2f(y1v[t]), y2 = bf2f(y2v[t]);
      a[0] += y0*y0; a[1] += y0*y1; a[2] += y0*y2;
      a[3] += y1*y1; a[4] += y1*y2; a[5] += y2*y2;
    }
  }
  __shared__ float red[4][6];
  const int lane = threadIdx.x & 63, wid = threadIdx.x >> 6;
  #pragma unroll
  for (int t = 0; t < 6; t++) {
    float v = a[t];
    v += __shfl_xor(v, 1);  v += __shfl_xor(v, 2);  v += __shfl_xor(v, 4);
    v += __shfl_xor(v, 8);  v += __shfl_xor(v, 16); v += __shfl_xor(v, 32);
    a[t] = v;
  }
  if (lane == 0)
    #pragma unroll
    for (int t = 0; t < 6; t++) red[wid][t] = a[t];
  __syncthreads();
  if (threadIdx.x < 6)
    atomicAdd(&G[threadIdx.x], red[0][threadIdx.x] + red[1][threadIdx.x] +
                               red[2][threadIdx.x] + red[3][threadIdx.x]);
}

// ---------------- Nash iterations + aux loss + both Sinkhorns (scalar) ----------------
__global__ void head_k(float* SC, const float* __restrict__ agg, const float* __restrict__ mA,
                       const float* __restrict__ mF, float* __restrict__ aux_out) {
  if (threadIdx.x != 0 || blockIdx.x != 0) return;
  float G[6];
  for (int t = 0; t < 6; t++) G[t] = SC[t];
  const int gi[3][3] = {{0,1,2},{1,3,4},{2,4,5}};
  float a[3] = {agg[0], agg[1], agg[2]};
  float w[3];
  {
    float m = fmaxf(a[0], fmaxf(a[1], a[2])); float s = 0.f;
    for (int l = 0; l < 3; l++) { w[l] = expf(a[l]-m); s += w[l]; }
    for (int l = 0; l < 3; l++) w[l] /= s;
  }
  const float inv = 1.f / (float)CNT;
  for (int it = 0; it < 3; it++) {
    float q = 0.f;
    for (int l = 0; l < 3; l++) for (int m2 = 0; m2 < 3; m2++) q += w[l]*w[m2]*G[gi[l][m2]];
    float z[3];
    for (int l = 0; l < 3; l++) {
      float dot = w[0]*G[gi[l][0]] + w[1]*G[gi[l][1]] + w[2]*G[gi[l][2]];
      z[l] = a[l] - (G[gi[l][l]] - 2.f*dot + q) * inv;
    }
    float m = fmaxf(z[0], fmaxf(z[1], z[2])); float s = 0.f;
    for (int l = 0; l < 3; l++) { w[l] = expf(z[l]-m); s += w[l]; }
    for (int l = 0; l < 3; l++) w[l] /= s;
  }
  SC[6] = w[0]; SC[7] = w[1]; SC[8] = w[2];
  aux_out[0] = w[0]*logf(w[0]*3.f + 1e-9f) + w[1]*logf(w[1]*3.f + 1e-9f) + w[2]*logf(w[2]*3.f + 1e-9f);
  for (int which = 0; which < 2; which++) {
    const float* Lg = which ? mF : mA;
    float M0 = expf(Lg[0]), M1 = expf(Lg[1]), M2 = expf(Lg[2]), M3 = expf(Lg[3]);
    for (int i2 = 0; i2 < 10; i2++) {
      float r0 = M0+M1, r1 = M2+M3; M0 /= r0; M1 /= r0; M2 /= r1; M3 /= r1;
      float c0 = M0+M2, c1 = M1+M3; M0 /= c0; M2 /= c0; M1 /= c1; M3 /= c1;
    }
    SC[9 + which*2] = M0; SC[10 + which*2] = M1;
  }
}

// ---------------- fused mix1 + FFN RMSNorm: one row per block ----------------
__global__ __launch_bounds__(256) void mixrms_k(const float* __restrict__ x, const u16* __restrict__ Y0,
                                                const u16* __restrict__ Y1, const u16* __restrict__ Y2,
                                                const float* __restrict__ SC, const float* __restrict__ w2,
                                                float* __restrict__ x1, u16* __restrict__ xn2) {
  const float w0 = SC[6], w1 = SC[7], ww2 = SC[8], p0 = SC[9], p1 = SC[10];
  const int i = blockIdx.x;
  const int b = i >> 11, n = i & 2047;
  const float* xr = x + (size_t)i * D_;
  const u16* y0 = Y0 + (size_t)i * D_;
  const u16* y1 = Y1 + (size_t)(b*1024 + (n>>1)) * D_;
  const u16* y2 = Y2 + (size_t)(b*512  + (n>>2)) * D_;
  float xv[4], wv[4];
  float ss = 0.f;
  #pragma unroll
  for (int t = 0; t < 4; t++) {
    int c = threadIdx.x + t*256;
    float v = p0*xr[c] + p1*(w0*bf2f(y0[c]) + w1*bf2f(y1[c]) + ww2*bf2f(y2[c]));
    xv[t] = v; wv[t] = w2[c]; ss += v*v;
    x1[(size_t)i*D_ + c] = v;
  }
  #pragma unroll
  for (int o = 1; o < 64; o <<= 1) ss += __shfl_xor(ss, o);
  __shared__ float red[4];
  if ((threadIdx.x & 63) == 0) red[threadIdx.x >> 6] = ss;
  __syncthreads();
  float sc = rsqrtf((red[0]+red[1]+red[2]+red[3]) * (1.f/D_) + 1e-6f);
  #pragma unroll
  for (int t = 0; t < 4; t++) {
    int c = threadIdx.x + t*256;
    xn2[(size_t)i*D_ + c] = f2bf(xv[t]*wv[t]*sc);
  }
}

// ================================ host launcher ================================
extern "C" void kernel_launch(void* const* d_in, const int* in_sizes, int n_in,
                              void* d_out, int out_size, void* d_ws, size_t ws_size,
                              hipStream_t stream) {
  (void)in_sizes; (void)n_in; (void)out_size; (void)ws_size;
  const float* x    = (const float*)d_in[0];
  const float* nw1  = (const float*)d_in[1];
  const float* nw2  = (const float*)d_in[2];
  const float* Wdec = (const float*)d_in[3];
  const float* Wq   = (const float*)d_in[4];
  const float* Wk   = (const float*)d_in[5];
  const float* Wv   = (const float*)d_in[6];
  const float* Wo   = (const float*)d_in[7];
  const float* agg  = (const float*)d_in[8];
  const float* Wg   = (const float*)d_in[9];
  const float* Wu   = (const float*)d_in[10];
  const float* Wdn  = (const float*)d_in[11];
  const float* mA   = (const float*)d_in[12];
  const float* mF   = (const float*)d_in[13];
  float* out = (float*)d_out;

  char* ws = (char*)d_ws;
  size_t off = 0;
  auto take = [&](size_t b) { size_t r = off; off += (b + 255) & ~(size_t)255; return r; };

  u16* A_wp  = (u16*)(ws + take((size_t)9216*1024*2));
  u16* WdecB = (u16*)(ws + take((size_t)3*1024*1024*2));
  u16* Wqkv  = (u16*)(ws + take((size_t)9216*1024*2));
  u16* BTgu  = (u16*)(ws + take((size_t)5632*1024*2));   // gate/up 16-col interleaved
  u16* WdnT  = (u16*)(ws + take((size_t)HIDP*1024*2));
  u16* WoT   = (u16*)(ws + take((size_t)1024*1024*2));
  u16* xn_all = (u16*)(ws + take((size_t)7168*1024*2));
  float* x1  = (float*)(ws + take((size_t)CNT*4));
  float* SCb = (float*)(ws + take(256));
  char*  big = ws + take(88080384);
  // attention phase
  u16*   QKV   = (u16*)big;                              // [7168, 3072] bf16 (V cols unused)
  u16*   VTa   = (u16*)(big + 44040192);                 // per-level [b][1024][Nl]
  u16*   Ob    = (u16*)(big + 58720256);                 // [7168, 1024] bf16
  u16*   YC    = (u16*)(big + 73400320);                 // [7168, 1024] bf16
  // FFN phase alias (attention working set dead by then; YC region untouched)
  u16*   hbuf  = (u16*)big;                              // [4096, 2816] bf16

  dim3 blk(256);
  const int BIG = 1 << 30;

  // ---- 1: all weight prep in one launch (+ SCb zero + BTgu pad zero) ----
  wprep_k<<<21924, blk, 0, stream>>>(Wdec, Wq, Wk, Wv, Wo, Wg, Wu, Wdn,
                                     A_wp, WdecB, WoT, BTgu, WdnT, SCb);
  // ---- 2: fused QKV weights: F_l^T = [Wq|Wk|Wv]_l^T x Wdec_l^T ----
  gemm_t<4,1><<<dim3(8, 72), blk, 0, stream>>>(A_wp, WdecB, Wqkv, nullptr, nullptr, nullptr,
                                               1024, 1024, 24, 48, 1024u*1024u);
  // ---- 3-4: attention RMSNorm (+pool1 fused), pool2 ----
  rmsA_k<<<2048, blk, 0, stream>>>(x, nw1, xn_all, xn_all + (size_t)4096*1024);
  pool_k<<<512, blk, 0, stream>>>(xn_all + (size_t)4096*1024, xn_all + (size_t)6144*1024, 9);
  // ---- 5: QKV GEMM (per-level weight select) + fused V transpose epilogue ----
  gemm_t<4,4><<<dim3(24, 56), blk, 0, stream>>>(xn_all, Wqkv, QKV, VTa, nullptr, nullptr,
                                                3072, 1024, 32, 48, 3072u*1024u);
  // ---- 6: flash attention (all levels) ----
  flash_k<<<896, blk, 0, stream>>>(QKV, VTa, Ob);
  // ---- 7: output projection -> YC (bf16) ----
  gemm_t<4,1><<<dim3(8, 56), blk, 0, stream>>>(Ob, WoT, YC, nullptr, nullptr, nullptr,
                                               1024, 1024, BIG, BIG, 0u);
  // ---- 8-9: Nash via Gram + scalar head ----
  u16* YC1 = YC + (size_t)4096*1024;
  u16* YC2 = YC + (size_t)6144*1024;
  gram_k<<<1024, blk, 0, stream>>>(YC, YC1, YC2, SCb);
  head_k<<<1, 64, 0, stream>>>(SCb, agg, mA, mF, out + CNT);
  // ---- 10: mix1 + FFN RMSNorm fused ----
  mixrms_k<<<4096, blk, 0, stream>>>(x, YC, YC1, YC2, SCb, nw2, x1, xn_all);
  // ---- 11: gate/up GEMM with fused silu*mul epilogue ----
  gemm_t<4,3><<<dim3(44, 32), blk, 0, stream>>>(xn_all, BTgu, hbuf, nullptr, nullptr, nullptr,
                                                5632, 1024, BIG, BIG, 0u);
  // ---- 12: down GEMM with fused final residual mix ----
  gemm_t<4,2><<<dim3(8, 32), blk, 0, stream>>>(hbuf, WdnT, out, nullptr, x1, SCb,
                                               1024, HIDP, BIG, BIG, 0u);
}